// Round 5
// baseline (470.157 us; speedup 1.0000x reference)
//
#include <hip/hip_runtime.h>
#include <stdint.h>

#define N_ROWS 32768
#define DIM    256
#define KCODES 8192
#define KSPLIT 8
#define KPS    (KCODES / KSPLIT)   /* 1024 codes per split */
#define BM     256
#define BN     64
#define NT     (KPS / BN)          /* 16 tiles */
#define THREADS 256

typedef int   v4i  __attribute__((ext_vector_type(4)));
typedef int   v8i  __attribute__((ext_vector_type(8)));
typedef float v16f __attribute__((ext_vector_type(16)));

__device__ __forceinline__ void gload_lds16(const void* g, void* l) {
  __builtin_amdgcn_global_load_lds((const __attribute__((address_space(1))) uint32_t*)g,
                                   (__attribute__((address_space(3))) uint32_t*)l, 16, 0, 0);
}

// ------- Kernel A: w -> fp8(-w*2^13), bp = (1 + sum(w^2)) * 4096 -------------
__global__ void kconv(const float* __restrict__ wgt, uint32_t* __restrict__ wb8,
                      float* __restrict__ bp) {
  const int code = blockIdx.x * 4 + (threadIdx.x >> 6);
  const int l = threadIdx.x & 63;
  float4 v = *(const float4*)(wgt + (size_t)code * DIM + l * 4);
  float s = v.x * v.x + v.y * v.y + v.z * v.z + v.w * v.w;
  int u = __builtin_amdgcn_cvt_pk_fp8_f32(v.x * -8192.f, v.y * -8192.f, 0, false);
  u = __builtin_amdgcn_cvt_pk_fp8_f32(v.z * -8192.f, v.w * -8192.f, u, true);
  wb8[(size_t)code * 64 + l] = (uint32_t)u;
  for (int o = 32; o; o >>= 1) s += __shfl_down(s, o, 64);
  if (l == 0) bp[code] = (1.0f + s) * 4096.f;
}

// ---------------- Kernel B: fp8 MX-MFMA distance argmin ----------------------
__global__ __launch_bounds__(THREADS, 4) void kmain(
    const float* __restrict__ x, const uint32_t* __restrict__ wb8,
    const float* __restrict__ bp, uint64_t* __restrict__ cand) {
  __shared__ __align__(16) uint8_t sm[32768];    // A stage pass / 2 x 16KB B buf
  __shared__ __align__(16) float bpl[KPS];       // 4KB
  const int rb = blockIdx.x * BM;
  const int sp = blockIdx.y;
  const int k0 = sp * KPS;
  const int t = threadIdx.x;
  const int wv = t >> 6, l = t & 63, l31 = l & 31, h = l >> 5;
  const int m7 = l31 & 7;

  // ---- bp slice (pre-scaled by kconv) -> LDS, 1KB per wave ----
  gload_lds16(bp + k0 + wv * 256 + l * 4, (uint8_t*)bpl + wv * 1024);

  // ---- A prologue: x fp32 -> fp8 -> LDS (16B-swizzled) -> registers ----
  v8i afr[2][4];
  for (int p = 0; p < 2; ++p) {
    for (int it = 0; it < 32; ++it) {
      int e = it * 1024 + t * 4;
      int r = e >> 8, cb = e & 255;
      float4 xv = *(const float4*)(x + (size_t)(rb + p * 128 + r) * DIM + cb);
      int u = __builtin_amdgcn_cvt_pk_fp8_f32(xv.x, xv.y, 0, false);
      u = __builtin_amdgcn_cvt_pk_fp8_f32(xv.z, xv.w, u, true);
      *(int*)(sm + r * 256 + (((cb >> 4) ^ (r & 7)) << 4) + (cb & 15)) = u;
    }
    __syncthreads();
    if ((wv >> 1) == p) {
      int rw = (wv & 1) * 64;
#pragma unroll
      for (int mi = 0; mi < 2; ++mi)
#pragma unroll
        for (int ks = 0; ks < 4; ++ks) {
          int r = rw + mi * 32 + l31;
          const uint8_t* rp = sm + r * 256;
          int sa = (ks * 4 + h * 2) ^ m7;
          v4i lo = *(const v4i*)(rp + sa * 16);
          v4i hi = *(const v4i*)(rp + (sa ^ 1) * 16);
          v8i f;
          f[0] = lo[0]; f[1] = lo[1]; f[2] = lo[2]; f[3] = lo[3];
          f[4] = hi[0]; f[5] = hi[1]; f[6] = hi[2]; f[7] = hi[3];
          afr[mi][ks] = f;
        }
    }
    __syncthreads();
  }

  uint32_t mp[2][16];
#pragma unroll
  for (int mi = 0; mi < 2; ++mi)
#pragma unroll
    for (int j = 0; j < 16; ++j) mp[mi][j] = 0xFFFFFFFFu;

  auto stage = [&](int kt, int buf) {
    const uint32_t* src = wb8 + (size_t)(k0 + kt * BN) * 64;
#pragma unroll
    for (int i = 0; i < 4; ++i) {
      int r0 = (wv * 4 + i) * 4;
      int r = r0 + (l >> 4);
      int c = (l & 15) ^ (r & 7);                 // pre-swizzled 16B source slot
      gload_lds16(src + r * 64 + c * 4, sm + buf * 16384 + r0 * 256);
    }
  };

  stage(0, 0);
  __syncthreads();

  for (int kt = 0; kt < NT; ++kt) {
    const int cur = kt & 1;
    if (kt + 1 < NT) stage(kt + 1, cur ^ 1);
    const uint8_t* sb = sm + cur * 16384;
#pragma unroll
    for (int nb = 0; nb < 2; ++nb) {
      float bpv = bpl[kt * 64 + nb * 32 + l31];
      v16f acc0, acc1;
#pragma unroll
      for (int z = 0; z < 16; ++z) { acc0[z] = bpv; acc1[z] = bpv; }
      __builtin_amdgcn_s_setprio(1);
#pragma unroll
      for (int ks = 0; ks < 4; ++ks) {
        int r = nb * 32 + l31;
        const uint8_t* rp = sb + r * 256;
        int sa = (ks * 4 + h * 2) ^ m7;
        v4i lo = *(const v4i*)(rp + sa * 16);
        v4i hi = *(const v4i*)(rp + (sa ^ 1) * 16);
        v8i bf;
        bf[0] = lo[0]; bf[1] = lo[1]; bf[2] = lo[2]; bf[3] = lo[3];
        bf[4] = hi[0]; bf[5] = hi[1]; bf[6] = hi[2]; bf[7] = hi[3];
        // acc = bp*4096 + dot(x, -8192*w) = 4096 * (sqdist - |x|^2)
        acc0 = __builtin_amdgcn_mfma_scale_f32_32x32x64_f8f6f4(
            afr[0][ks], bf, acc0, 0, 0, 0, 127, 0, 127);
        acc1 = __builtin_amdgcn_mfma_scale_f32_32x32x64_f8f6f4(
            afr[1][ks], bf, acc1, 0, 0, 0, 127, 0, 127);
      }
      __builtin_amdgcn_s_setprio(0);
      // pack (slot, lane) into the 10 noise bits of the mantissa; min_u32
      const uint32_t vslot = ((uint32_t)(kt * 2 + nb) << 5) | (uint32_t)l31;
#pragma unroll
      for (int j = 0; j < 16; ++j) {
        uint32_t p0 = __float_as_uint(acc0[j]) | vslot;
        mp[0][j] = p0 < mp[0][j] ? p0 : mp[0][j];
        uint32_t p1 = __float_as_uint(acc1[j]) | vslot;
        mp[1][j] = p1 < mp[1][j] ? p1 : mp[1][j];
      }
    }
    __builtin_amdgcn_sched_barrier(0);
    asm volatile("s_waitcnt vmcnt(0)" ::: "memory");
    __builtin_amdgcn_s_barrier();
    __builtin_amdgcn_sched_barrier(0);
  }

  // ---- cross-lane argmin over the 32 code-columns, write candidates ----
#pragma unroll
  for (int mi = 0; mi < 2; ++mi)
#pragma unroll
    for (int j = 0; j < 16; ++j) {
      uint32_t pv = mp[mi][j];
#pragma unroll
      for (int o = 1; o < 32; o <<= 1) {
        uint32_t ov = (uint32_t)__shfl_xor((int)pv, o, 64);
        pv = ov < pv ? ov : pv;
      }
      if (l31 == 0) {
        uint32_t slot = (pv >> 5) & 31u, lw = pv & 31u;
        uint32_t kg = (uint32_t)k0 + (slot >> 1) * 64 + (slot & 1) * 32 + lw;
        int row = rb + wv * 64 + mi * 32 + (j & 3) + 8 * (j >> 2) + 4 * h;
        cand[(size_t)row * KSPLIT + sp] = ((uint64_t)pv << 13) | (uint64_t)kg;
      }
    }
}

// ---------------- Kernel C: combine splits, gather, out, loss partials -------
__global__ void kout(const float* __restrict__ x, const float* __restrict__ wgt,
                     const uint64_t* __restrict__ cand, float* __restrict__ out,
                     float* __restrict__ partial) {
  const int t = threadIdx.x;
  const int rb = blockIdx.x * 64;
  __shared__ int sk[64];
  __shared__ float red[4];
  if (t < 64) {
    const uint64_t* c = cand + (size_t)(rb + t) * KSPLIT;
    uint64_t P = c[0];
#pragma unroll
    for (int i = 1; i < KSPLIT; ++i) P = c[i] < P ? c[i] : P;
    sk[t] = (int)(P & 8191u);
  }
  __syncthreads();
  float acc = 0.f;
  for (int r = 0; r < 64; ++r) {
    int k = sk[r];
    float qv = wgt[(size_t)k * DIM + t];
    float xv = x[(size_t)(rb + r) * DIM + t];
    out[(size_t)(rb + r) * DIM + t] = qv;
    float d = xv - qv;
    acc = fmaf(d, d, acc);
  }
  for (int o = 32; o; o >>= 1) acc += __shfl_down(acc, o, 64);
  if ((t & 63) == 0) red[t >> 6] = acc;
  __syncthreads();
  if (t == 0) partial[blockIdx.x] = red[0] + red[1] + red[2] + red[3];
}

// ---------------- Kernel D: final loss ---------------------------------------
__global__ void kloss(const float* __restrict__ partial, float* __restrict__ lossout) {
  const int t = threadIdx.x;
  float s = partial[t] + partial[t + 256];
  for (int o = 32; o; o >>= 1) s += __shfl_down(s, o, 64);
  __shared__ float red[4];
  if ((t & 63) == 0) red[t >> 6] = s;
  __syncthreads();
  if (t == 0) lossout[0] = 1.5f * (red[0] + red[1] + red[2] + red[3]) /
                           (float)((size_t)N_ROWS * DIM);
}

extern "C" void kernel_launch(void* const* d_in, const int* in_sizes, int n_in,
                              void* d_out, int out_size, void* d_ws, size_t ws_size,
                              hipStream_t stream) {
  const float* x   = (const float*)d_in[0];
  const float* wgt = (const float*)d_in[1];
  float* out = (float*)d_out;
  uint8_t* ws = (uint8_t*)d_ws;
  uint32_t* wb8     = (uint32_t*)ws;                                    // 2 MB
  float*    bp      = (float*)(ws + (2u << 20));                        // 32 KB
  uint64_t* cand    = (uint64_t*)(ws + (2u << 20) + (64u << 10));       // 2 MB
  float*    partial = (float*)(ws + (2u << 20) + (64u << 10) + (2u << 20)); // 2 KB

  kconv<<<KCODES / 4, 256, 0, stream>>>(wgt, wb8, bp);
  dim3 g(N_ROWS / BM, KSPLIT);
  kmain<<<g, THREADS, 0, stream>>>(x, wb8, bp, cand);
  kout<<<N_ROWS / 64, 256, 0, stream>>>(x, wgt, cand, out, partial);
  kloss<<<1, 256, 0, stream>>>(partial, out + (size_t)N_ROWS * DIM);
}

// Round 6
// 184.727 us; speedup vs baseline: 2.5451x; 2.5451x over previous
//
#include <hip/hip_runtime.h>
#include <stdint.h>

#define N_ROWS 32768
#define DIM    256
#define KCODES 8192
#define KSPLIT 8
#define KPS    (KCODES / KSPLIT)   /* 1024 codes per split */
#define BM     256
#define BN     64
#define NT     (KPS / BN)          /* 16 tiles */
#define THREADS 512

typedef int   v4i  __attribute__((ext_vector_type(4)));
typedef int   v8i  __attribute__((ext_vector_type(8)));
typedef float v16f __attribute__((ext_vector_type(16)));

__device__ __forceinline__ void gload_lds16(const void* g, void* l) {
  __builtin_amdgcn_global_load_lds((const __attribute__((address_space(1))) uint32_t*)g,
                                   (__attribute__((address_space(3))) uint32_t*)l, 16, 0, 0);
}

// ------- Kernel A: w -> fp8(-w*2^13), bp = (1 + sum(w^2)) * 4096 -------------
__global__ void kconv(const float* __restrict__ wgt, uint32_t* __restrict__ wb8,
                      float* __restrict__ bp) {
  const int code = blockIdx.x * 4 + (threadIdx.x >> 6);
  const int l = threadIdx.x & 63;
  float4 v = *(const float4*)(wgt + (size_t)code * DIM + l * 4);
  float s = v.x * v.x + v.y * v.y + v.z * v.z + v.w * v.w;
  int u = __builtin_amdgcn_cvt_pk_fp8_f32(v.x * -8192.f, v.y * -8192.f, 0, false);
  u = __builtin_amdgcn_cvt_pk_fp8_f32(v.z * -8192.f, v.w * -8192.f, u, true);
  wb8[(size_t)code * 64 + l] = (uint32_t)u;
  for (int o = 32; o; o >>= 1) s += __shfl_down(s, o, 64);
  if (l == 0) bp[code] = (1.0f + s) * 4096.f;
}

// ---------------- Kernel B: fp8 MX-MFMA distance argmin ----------------------
// 8 waves x 32 rows each; 3-buffer depth-2 B prefetch; bp in MFMA C-operand.
__global__ __launch_bounds__(THREADS, 4) void kmain(
    const float* __restrict__ x, const uint32_t* __restrict__ wb8,
    const float* __restrict__ bp, uint64_t* __restrict__ cand) {
  __shared__ __align__(16) uint8_t sm[49152];    // 3 x 16KB B buffers / A pass
  __shared__ __align__(16) float bpl[KPS];       // 4KB
  const int rb = blockIdx.x * BM;
  const int sp = blockIdx.y;
  const int k0 = sp * KPS;
  const int t = threadIdx.x;
  const int wv = t >> 6, l = t & 63, l31 = l & 31, h = l >> 5;
  const int m7 = l31 & 7;

  // ---- bp slice (pre-scaled by kconv) -> LDS, waves 0-3, 1KB each ----
  if (wv < 4)
    gload_lds16(bp + k0 + wv * 256 + l * 4, (uint8_t*)bpl + wv * 1024);

  // ---- A prologue: x fp32 -> fp8 -> LDS (16B-swizzled) -> registers ----
  // pass p stages rows [p*128, p*128+128); waves p*4..p*4+3 read fragments.
  v8i afr[4];
  for (int p = 0; p < 2; ++p) {
    for (int it = 0; it < 16; ++it) {
      int e = it * 2048 + t * 4;
      int r = e >> 8, cb = e & 255;
      float4 xv = *(const float4*)(x + (size_t)(rb + p * 128 + r) * DIM + cb);
      int u = __builtin_amdgcn_cvt_pk_fp8_f32(xv.x, xv.y, 0, false);
      u = __builtin_amdgcn_cvt_pk_fp8_f32(xv.z, xv.w, u, true);
      *(int*)(sm + r * 256 + (((cb >> 4) ^ (r & 7)) << 4) + (cb & 15)) = u;
    }
    __syncthreads();
    if ((wv >> 2) == p) {
      int lr = (wv & 3) * 32 + l31;               // row within this 128-row pass
      const uint8_t* rp = sm + lr * 256;
#pragma unroll
      for (int ks = 0; ks < 4; ++ks) {
        int sa = (ks * 4 + h * 2) ^ m7;
        v4i lo = *(const v4i*)(rp + sa * 16);
        v4i hi = *(const v4i*)(rp + (sa ^ 1) * 16);
        v8i f;
        f[0] = lo[0]; f[1] = lo[1]; f[2] = lo[2]; f[3] = lo[3];
        f[4] = hi[0]; f[5] = hi[1]; f[6] = hi[2]; f[7] = hi[3];
        afr[ks] = f;
      }
    }
    __syncthreads();
  }

  uint32_t mp[16];
#pragma unroll
  for (int j = 0; j < 16; ++j) mp[j] = 0xFFFFFFFFu;

  // B stage: 64 codes x 256B = 16KB; 8 waves x 2 DMA instrs (8 rows each).
  auto stage = [&](int kt, int buf) {
    const uint32_t* src = wb8 + (size_t)(k0 + kt * BN) * 64;
#pragma unroll
    for (int i = 0; i < 2; ++i) {
      int r0 = wv * 8 + i * 4;
      int r = r0 + (l >> 4);
      int c = (l & 15) ^ (r & 7);                 // pre-swizzled 16B source slot
      gload_lds16(src + r * 64 + c * 4, sm + buf * 16384 + r0 * 256);
    }
  };

  stage(0, 0);
  stage(1, 1);
  __syncthreads();                                 // full drain once at start

  int bc = 0, b1 = 1, b2 = 2;
  for (int kt = 0; kt < NT; ++kt) {
    if (kt + 2 < NT) stage(kt + 2, b2);
    const uint8_t* sb = sm + bc * 16384;
#pragma unroll
    for (int nb = 0; nb < 2; ++nb) {
      float bpv = bpl[kt * 64 + nb * 32 + l31];
      v16f acc;
#pragma unroll
      for (int z = 0; z < 16; ++z) acc[z] = bpv;
      __builtin_amdgcn_s_setprio(1);
#pragma unroll
      for (int ks = 0; ks < 4; ++ks) {
        int r = nb * 32 + l31;
        const uint8_t* rp = sb + r * 256;
        int sa = (ks * 4 + h * 2) ^ m7;
        v4i lo = *(const v4i*)(rp + sa * 16);
        v4i hi = *(const v4i*)(rp + (sa ^ 1) * 16);
        v8i bf;
        bf[0] = lo[0]; bf[1] = lo[1]; bf[2] = lo[2]; bf[3] = lo[3];
        bf[4] = hi[0]; bf[5] = hi[1]; bf[6] = hi[2]; bf[7] = hi[3];
        // acc = bp*4096 + dot(x, -8192*w) = 4096 * (sqdist - |x|^2)
        acc = __builtin_amdgcn_mfma_scale_f32_32x32x64_f8f6f4(
            afr[ks], bf, acc, 0, 0, 0, 127, 0, 127);
      }
      __builtin_amdgcn_s_setprio(0);
      // pack (slot, lane) into the 10 noise bits of the mantissa; min_u32
      const uint32_t vslot = ((uint32_t)(kt * 2 + nb) << 5) | (uint32_t)l31;
#pragma unroll
      for (int j = 0; j < 16; ++j) {
        uint32_t p0 = __float_as_uint(acc[j]) | vslot;
        mp[j] = p0 < mp[j] ? p0 : mp[j];
      }
    }
    // counted vmcnt: drain tile kt+1's 2 loads, keep kt+2's 2 in flight
    __builtin_amdgcn_sched_barrier(0);
    if (kt + 2 < NT) { asm volatile("s_waitcnt vmcnt(2)" ::: "memory"); }
    else             { asm volatile("s_waitcnt vmcnt(0)" ::: "memory"); }
    __builtin_amdgcn_s_barrier();
    __builtin_amdgcn_sched_barrier(0);
    int tmp = bc; bc = b1; b1 = b2; b2 = tmp;
  }

  // ---- cross-lane argmin over the 32 code-columns, write candidates ----
#pragma unroll
  for (int j = 0; j < 16; ++j) {
    uint32_t pv = mp[j];
#pragma unroll
    for (int o = 1; o < 32; o <<= 1) {
      uint32_t ov = (uint32_t)__shfl_xor((int)pv, o, 64);
      pv = ov < pv ? ov : pv;
    }
    if (l31 == 0) {
      uint32_t slot = (pv >> 5) & 31u, lw = pv & 31u;
      uint32_t kg = (uint32_t)k0 + (slot >> 1) * 64 + (slot & 1) * 32 + lw;
      int row = rb + wv * 32 + (j & 3) + 8 * (j >> 2) + 4 * h;
      cand[(size_t)row * KSPLIT + sp] = ((uint64_t)pv << 13) | (uint64_t)kg;
    }
  }
}

// ---------------- Kernel C: combine splits, gather, out, loss partials -------
__global__ void kout(const float* __restrict__ x, const float* __restrict__ wgt,
                     const uint64_t* __restrict__ cand, float* __restrict__ out,
                     float* __restrict__ partial) {
  const int t = threadIdx.x;
  const int rb = blockIdx.x * 64;
  __shared__ int sk[64];
  __shared__ float red[4];
  if (t < 64) {
    const uint64_t* c = cand + (size_t)(rb + t) * KSPLIT;
    uint64_t P = c[0];
#pragma unroll
    for (int i = 1; i < KSPLIT; ++i) P = c[i] < P ? c[i] : P;
    sk[t] = (int)(P & 8191u);
  }
  __syncthreads();
  float acc = 0.f;
  for (int r = 0; r < 64; ++r) {
    int k = sk[r];
    float qv = wgt[(size_t)k * DIM + t];
    float xv = x[(size_t)(rb + r) * DIM + t];
    out[(size_t)(rb + r) * DIM + t] = qv;
    float d = xv - qv;
    acc = fmaf(d, d, acc);
  }
  for (int o = 32; o; o >>= 1) acc += __shfl_down(acc, o, 64);
  if ((t & 63) == 0) red[t >> 6] = acc;
  __syncthreads();
  if (t == 0) partial[blockIdx.x] = red[0] + red[1] + red[2] + red[3];
}

// ---------------- Kernel D: final loss ---------------------------------------
__global__ void kloss(const float* __restrict__ partial, float* __restrict__ lossout) {
  const int t = threadIdx.x;
  float s = partial[t] + partial[t + 256];
  for (int o = 32; o; o >>= 1) s += __shfl_down(s, o, 64);
  __shared__ float red[4];
  if ((t & 63) == 0) red[t >> 6] = s;
  __syncthreads();
  if (t == 0) lossout[0] = 1.5f * (red[0] + red[1] + red[2] + red[3]) /
                           (float)((size_t)N_ROWS * DIM);
}

extern "C" void kernel_launch(void* const* d_in, const int* in_sizes, int n_in,
                              void* d_out, int out_size, void* d_ws, size_t ws_size,
                              hipStream_t stream) {
  const float* x   = (const float*)d_in[0];
  const float* wgt = (const float*)d_in[1];
  float* out = (float*)d_out;
  uint8_t* ws = (uint8_t*)d_ws;
  uint32_t* wb8     = (uint32_t*)ws;                                    // 2 MB
  float*    bp      = (float*)(ws + (2u << 20));                        // 32 KB
  uint64_t* cand    = (uint64_t*)(ws + (2u << 20) + (64u << 10));       // 2 MB
  float*    partial = (float*)(ws + (2u << 20) + (64u << 10) + (2u << 20)); // 2 KB

  kconv<<<KCODES / 4, 256, 0, stream>>>(wgt, wb8, bp);
  dim3 g(N_ROWS / BM, KSPLIT);
  kmain<<<g, THREADS, 0, stream>>>(x, wb8, bp, cand);
  kout<<<N_ROWS / 64, 256, 0, stream>>>(x, wgt, cand, out, partial);
  kloss<<<1, 256, 0, stream>>>(partial, out + (size_t)N_ROWS * DIM);
}

// Round 7
// 107.295 us; speedup vs baseline: 4.3819x; 1.7217x over previous
//
#include <hip/hip_runtime.h>
#include <stdint.h>

#define N_ROWS 32768
#define DIM    256
#define KCODES 8192
#define KSPLIT 8
#define KPS    (KCODES / KSPLIT)   /* 1024 codes per split */
#define BM     256
#define BN     64
#define NT     (KPS / BN)          /* 16 tiles */
#define THREADS 256

typedef int   v4i  __attribute__((ext_vector_type(4)));
typedef int   v8i  __attribute__((ext_vector_type(8)));
typedef float v16f __attribute__((ext_vector_type(16)));

__device__ __forceinline__ void gload_lds16(const void* g, void* l) {
  __builtin_amdgcn_global_load_lds((const __attribute__((address_space(1))) uint32_t*)g,
                                   (__attribute__((address_space(3))) uint32_t*)l, 16, 0, 0);
}

// ------- Kernel A: w -> fp8(-w*2^13), bp = (1 + sum(w^2)) * 4096 -------------
__global__ void kconv(const float* __restrict__ wgt, uint32_t* __restrict__ wb8,
                      float* __restrict__ bp) {
  const int code = blockIdx.x * 4 + (threadIdx.x >> 6);
  const int l = threadIdx.x & 63;
  float4 v = *(const float4*)(wgt + (size_t)code * DIM + l * 4);
  float s = v.x * v.x + v.y * v.y + v.z * v.z + v.w * v.w;
  int u = __builtin_amdgcn_cvt_pk_fp8_f32(v.x * -8192.f, v.y * -8192.f, 0, false);
  u = __builtin_amdgcn_cvt_pk_fp8_f32(v.z * -8192.f, v.w * -8192.f, u, true);
  wb8[(size_t)code * 64 + l] = (uint32_t)u;
  for (int o = 32; o; o >>= 1) s += __shfl_down(s, o, 64);
  if (l == 0) bp[code] = (1.0f + s) * 4096.f;
}

// ---------------- Kernel B: fp8 MX-MFMA distance argmin ----------------------
// 4 waves x 64 rows; LDS 36.9KB -> 4 blocks/CU; no forced register cap.
__global__ __launch_bounds__(THREADS, 2) void kmain(
    const float* __restrict__ x, const uint32_t* __restrict__ wb8,
    const float* __restrict__ bp, uint64_t* __restrict__ cand) {
  __shared__ __align__(16) uint8_t sm[32768];    // A stage pass / 2 x 16KB B buf
  __shared__ __align__(16) float bpl[KPS];       // 4KB
  const int rb = blockIdx.x * BM;
  const int sp = blockIdx.y;
  const int k0 = sp * KPS;
  const int t = threadIdx.x;
  const int wv = t >> 6, l = t & 63, l31 = l & 31, h = l >> 5;
  const int m7 = l31 & 7;

  // ---- bp slice (pre-scaled by kconv) -> LDS, 1KB per wave ----
  gload_lds16(bp + k0 + wv * 256 + l * 4, (uint8_t*)bpl + wv * 1024);

  // ---- A prologue: x fp32 -> fp8 -> LDS (16B-swizzled) -> registers ----
  v8i afr[2][4];
  for (int p = 0; p < 2; ++p) {
    for (int it = 0; it < 32; ++it) {
      int e = it * 1024 + t * 4;
      int r = e >> 8, cb = e & 255;
      float4 xv = *(const float4*)(x + (size_t)(rb + p * 128 + r) * DIM + cb);
      int u = __builtin_amdgcn_cvt_pk_fp8_f32(xv.x, xv.y, 0, false);
      u = __builtin_amdgcn_cvt_pk_fp8_f32(xv.z, xv.w, u, true);
      *(int*)(sm + r * 256 + (((cb >> 4) ^ (r & 7)) << 4) + (cb & 15)) = u;
    }
    __syncthreads();
    if ((wv >> 1) == p) {
      int rw = (wv & 1) * 64;
#pragma unroll
      for (int mi = 0; mi < 2; ++mi)
#pragma unroll
        for (int ks = 0; ks < 4; ++ks) {
          int r = rw + mi * 32 + l31;
          const uint8_t* rp = sm + r * 256;
          int sa = (ks * 4 + h * 2) ^ m7;
          v4i lo = *(const v4i*)(rp + sa * 16);
          v4i hi = *(const v4i*)(rp + (sa ^ 1) * 16);
          v8i f;
          f[0] = lo[0]; f[1] = lo[1]; f[2] = lo[2]; f[3] = lo[3];
          f[4] = hi[0]; f[5] = hi[1]; f[6] = hi[2]; f[7] = hi[3];
          afr[mi][ks] = f;
        }
    }
    __syncthreads();
  }

  uint32_t mp[2][16];
#pragma unroll
  for (int mi = 0; mi < 2; ++mi)
#pragma unroll
    for (int j = 0; j < 16; ++j) mp[mi][j] = 0xFFFFFFFFu;

  auto stage = [&](int kt, int buf) {
    const uint32_t* src = wb8 + (size_t)(k0 + kt * BN) * 64;
#pragma unroll
    for (int i = 0; i < 4; ++i) {
      int r0 = (wv * 4 + i) * 4;
      int r = r0 + (l >> 4);
      int c = (l & 15) ^ (r & 7);                 // pre-swizzled 16B source slot
      gload_lds16(src + r * 64 + c * 4, sm + buf * 16384 + r0 * 256);
    }
  };

  stage(0, 0);
  __syncthreads();

  for (int kt = 0; kt < NT; ++kt) {
    const int cur = kt & 1;
    if (kt + 1 < NT) stage(kt + 1, cur ^ 1);
    const uint8_t* sb = sm + cur * 16384;
#pragma unroll
    for (int nb = 0; nb < 2; ++nb) {
      float bpv = bpl[kt * 64 + nb * 32 + l31];
      v16f acc0, acc1;
#pragma unroll
      for (int z = 0; z < 16; ++z) { acc0[z] = bpv; acc1[z] = bpv; }
      __builtin_amdgcn_s_setprio(1);
#pragma unroll
      for (int ks = 0; ks < 4; ++ks) {
        int r = nb * 32 + l31;
        const uint8_t* rp = sb + r * 256;
        int sa = (ks * 4 + h * 2) ^ m7;
        v4i lo = *(const v4i*)(rp + sa * 16);
        v4i hi = *(const v4i*)(rp + (sa ^ 1) * 16);
        v8i bf;
        bf[0] = lo[0]; bf[1] = lo[1]; bf[2] = lo[2]; bf[3] = lo[3];
        bf[4] = hi[0]; bf[5] = hi[1]; bf[6] = hi[2]; bf[7] = hi[3];
        // acc = bp*4096 + dot(x, -8192*w) = 4096 * (sqdist - |x|^2)
        acc0 = __builtin_amdgcn_mfma_scale_f32_32x32x64_f8f6f4(
            afr[0][ks], bf, acc0, 0, 0, 0, 127, 0, 127);
        acc1 = __builtin_amdgcn_mfma_scale_f32_32x32x64_f8f6f4(
            afr[1][ks], bf, acc1, 0, 0, 0, 127, 0, 127);
      }
      __builtin_amdgcn_s_setprio(0);
      // pack (slot, lane) into the 10 noise bits of the mantissa; min_u32
      const uint32_t vslot = ((uint32_t)(kt * 2 + nb) << 5) | (uint32_t)l31;
#pragma unroll
      for (int j = 0; j < 16; ++j) {
        uint32_t p0 = __float_as_uint(acc0[j]) | vslot;
        mp[0][j] = p0 < mp[0][j] ? p0 : mp[0][j];
        uint32_t p1 = __float_as_uint(acc1[j]) | vslot;
        mp[1][j] = p1 < mp[1][j] ? p1 : mp[1][j];
      }
    }
    __builtin_amdgcn_sched_barrier(0);
    asm volatile("s_waitcnt vmcnt(0)" ::: "memory");
    __builtin_amdgcn_s_barrier();
    __builtin_amdgcn_sched_barrier(0);
  }

  // ---- cross-lane argmin over the 32 code-columns, write candidates ----
#pragma unroll
  for (int mi = 0; mi < 2; ++mi)
#pragma unroll
    for (int j = 0; j < 16; ++j) {
      uint32_t pv = mp[mi][j];
#pragma unroll
      for (int o = 1; o < 32; o <<= 1) {
        uint32_t ov = (uint32_t)__shfl_xor((int)pv, o, 64);
        pv = ov < pv ? ov : pv;
      }
      if (l31 == 0) {
        uint32_t slot = (pv >> 5) & 31u, lw = pv & 31u;
        uint32_t kg = (uint32_t)k0 + (slot >> 1) * 64 + (slot & 1) * 32 + lw;
        int row = rb + wv * 64 + mi * 32 + (j & 3) + 8 * (j >> 2) + 4 * h;
        cand[(size_t)row * KSPLIT + sp] = ((uint64_t)pv << 13) | (uint64_t)kg;
      }
    }
}

// ---------------- Kernel C: combine splits, gather, out, loss partials -------
__global__ void kout(const float* __restrict__ x, const float* __restrict__ wgt,
                     const uint64_t* __restrict__ cand, float* __restrict__ out,
                     float* __restrict__ partial) {
  const int t = threadIdx.x;
  const int rb = blockIdx.x * 64;
  __shared__ int sk[64];
  __shared__ float red[4];
  if (t < 64) {
    const uint64_t* c = cand + (size_t)(rb + t) * KSPLIT;
    uint64_t P = c[0];
#pragma unroll
    for (int i = 1; i < KSPLIT; ++i) P = c[i] < P ? c[i] : P;
    sk[t] = (int)(P & 8191u);
  }
  __syncthreads();
  float acc = 0.f;
  for (int r = 0; r < 64; ++r) {
    int k = sk[r];
    float qv = wgt[(size_t)k * DIM + t];
    float xv = x[(size_t)(rb + r) * DIM + t];
    out[(size_t)(rb + r) * DIM + t] = qv;
    float d = xv - qv;
    acc = fmaf(d, d, acc);
  }
  for (int o = 32; o; o >>= 1) acc += __shfl_down(acc, o, 64);
  if ((t & 63) == 0) red[t >> 6] = acc;
  __syncthreads();
  if (t == 0) partial[blockIdx.x] = red[0] + red[1] + red[2] + red[3];
}

// ---------------- Kernel D: final loss ---------------------------------------
__global__ void kloss(const float* __restrict__ partial, float* __restrict__ lossout) {
  const int t = threadIdx.x;
  float s = partial[t] + partial[t + 256];
  for (int o = 32; o; o >>= 1) s += __shfl_down(s, o, 64);
  __shared__ float red[4];
  if ((t & 63) == 0) red[t >> 6] = s;
  __syncthreads();
  if (t == 0) lossout[0] = 1.5f * (red[0] + red[1] + red[2] + red[3]) /
                           (float)((size_t)N_ROWS * DIM);
}

extern "C" void kernel_launch(void* const* d_in, const int* in_sizes, int n_in,
                              void* d_out, int out_size, void* d_ws, size_t ws_size,
                              hipStream_t stream) {
  const float* x   = (const float*)d_in[0];
  const float* wgt = (const float*)d_in[1];
  float* out = (float*)d_out;
  uint8_t* ws = (uint8_t*)d_ws;
  uint32_t* wb8     = (uint32_t*)ws;                                    // 2 MB
  float*    bp      = (float*)(ws + (2u << 20));                        // 32 KB
  uint64_t* cand    = (uint64_t*)(ws + (2u << 20) + (64u << 10));       // 2 MB
  float*    partial = (float*)(ws + (2u << 20) + (64u << 10) + (2u << 20)); // 2 KB

  kconv<<<KCODES / 4, 256, 0, stream>>>(wgt, wb8, bp);
  dim3 g(N_ROWS / BM, KSPLIT);
  kmain<<<g, THREADS, 0, stream>>>(x, wb8, bp, cand);
  kout<<<N_ROWS / 64, 256, 0, stream>>>(x, wgt, cand, out, partial);
  kloss<<<1, 256, 0, stream>>>(partial, out + (size_t)N_ROWS * DIM);
}

// Round 8
// 96.880 us; speedup vs baseline: 4.8530x; 1.1075x over previous
//
#include <hip/hip_runtime.h>
#include <stdint.h>

#define N_ROWS 32768
#define DIM    256
#define KCODES 8192
#define KSPLIT 8
#define KPS    (KCODES / KSPLIT)   /* 1024 codes per split */
#define BM     128
#define BN     64
#define NT     (KPS / BN)          /* 16 tiles */
#define THREADS 256

typedef int   v4i  __attribute__((ext_vector_type(4)));
typedef int   v8i  __attribute__((ext_vector_type(8)));
typedef float v16f __attribute__((ext_vector_type(16)));

__device__ __forceinline__ void gload_lds16(const void* g, void* l) {
  __builtin_amdgcn_global_load_lds((const __attribute__((address_space(1))) uint32_t*)g,
                                   (__attribute__((address_space(3))) uint32_t*)l, 16, 0, 0);
}

// ------- Kernel A: w -> fp8(-w*2^13), bp = (1 + sum(w^2)) * 4096 -------------
__global__ void kconv(const float* __restrict__ wgt, uint32_t* __restrict__ wb8,
                      float* __restrict__ bp) {
  const int code = blockIdx.x * 4 + (threadIdx.x >> 6);
  const int l = threadIdx.x & 63;
  float4 v = *(const float4*)(wgt + (size_t)code * DIM + l * 4);
  float s = v.x * v.x + v.y * v.y + v.z * v.z + v.w * v.w;
  int u = __builtin_amdgcn_cvt_pk_fp8_f32(v.x * -8192.f, v.y * -8192.f, 0, false);
  u = __builtin_amdgcn_cvt_pk_fp8_f32(v.z * -8192.f, v.w * -8192.f, u, true);
  wb8[(size_t)code * 64 + l] = (uint32_t)u;
  for (int o = 32; o; o >>= 1) s += __shfl_down(s, o, 64);
  if (l == 0) bp[code] = (1.0f + s) * 4096.f;
}

// ---------------- Kernel B: fp8 MX-MFMA distance argmin ----------------------
// 4 waves x 32 rows; ~100 total regs (incl AGPR) -> 4 waves/SIMD from 4
// independent blocks; LDS 36.9KB -> 4 blocks/CU.
__global__ __launch_bounds__(THREADS, 4) void kmain(
    const float* __restrict__ x, const uint32_t* __restrict__ wb8,
    const float* __restrict__ bp, uint64_t* __restrict__ cand) {
  __shared__ __align__(16) uint8_t sm[32768];    // A stage pass / 2 x 16KB B buf
  __shared__ __align__(16) float bpl[KPS];       // 4KB
  const int rb = blockIdx.x * BM;
  const int sp = blockIdx.y;
  const int k0 = sp * KPS;
  const int t = threadIdx.x;
  const int wv = t >> 6, l = t & 63, l31 = l & 31, h = l >> 5;
  const int m7 = l31 & 7;

  // ---- bp slice (pre-scaled by kconv) -> LDS, 1KB per wave ----
  gload_lds16(bp + k0 + wv * 256 + l * 4, (uint8_t*)bpl + wv * 1024);

  // ---- A prologue: 128 rows of x fp32 -> fp8 -> LDS (swizzled) -> regs ----
  v8i afr[4];
  {
    for (int it = 0; it < 32; ++it) {
      int e = it * 1024 + t * 4;
      int r = e >> 8, cb = e & 255;
      float4 xv = *(const float4*)(x + (size_t)(rb + r) * DIM + cb);
      int u = __builtin_amdgcn_cvt_pk_fp8_f32(xv.x, xv.y, 0, false);
      u = __builtin_amdgcn_cvt_pk_fp8_f32(xv.z, xv.w, u, true);
      *(int*)(sm + r * 256 + (((cb >> 4) ^ (r & 7)) << 4) + (cb & 15)) = u;
    }
    __syncthreads();
    int r = wv * 32 + l31;
    const uint8_t* rp = sm + r * 256;
#pragma unroll
    for (int ks = 0; ks < 4; ++ks) {
      int sa = (ks * 4 + h * 2) ^ m7;
      v4i lo = *(const v4i*)(rp + sa * 16);
      v4i hi = *(const v4i*)(rp + (sa ^ 1) * 16);
      v8i f;
      f[0] = lo[0]; f[1] = lo[1]; f[2] = lo[2]; f[3] = lo[3];
      f[4] = hi[0]; f[5] = hi[1]; f[6] = hi[2]; f[7] = hi[3];
      afr[ks] = f;
    }
    __syncthreads();
  }

  uint32_t mp[16];
#pragma unroll
  for (int j = 0; j < 16; ++j) mp[j] = 0xFFFFFFFFu;

  auto stage = [&](int kt, int buf) {
    const uint32_t* src = wb8 + (size_t)(k0 + kt * BN) * 64;
#pragma unroll
    for (int i = 0; i < 4; ++i) {
      int r0 = (wv * 4 + i) * 4;
      int r = r0 + (l >> 4);
      int c = (l & 15) ^ (r & 7);                 // pre-swizzled 16B source slot
      gload_lds16(src + r * 64 + c * 4, sm + buf * 16384 + r0 * 256);
    }
  };

  stage(0, 0);
  __syncthreads();

  for (int kt = 0; kt < NT; ++kt) {
    const int cur = kt & 1;
    if (kt + 1 < NT) stage(kt + 1, cur ^ 1);
    const uint8_t* sb = sm + cur * 16384;
#pragma unroll
    for (int nb = 0; nb < 2; ++nb) {
      float bpv = bpl[kt * 64 + nb * 32 + l31];
      v16f acc;
#pragma unroll
      for (int z = 0; z < 16; ++z) acc[z] = bpv;
      __builtin_amdgcn_s_setprio(1);
#pragma unroll
      for (int ks = 0; ks < 4; ++ks) {
        int r = nb * 32 + l31;
        const uint8_t* rp = sb + r * 256;
        int sa = (ks * 4 + h * 2) ^ m7;
        v4i lo = *(const v4i*)(rp + sa * 16);
        v4i hi = *(const v4i*)(rp + (sa ^ 1) * 16);
        v8i bf;
        bf[0] = lo[0]; bf[1] = lo[1]; bf[2] = lo[2]; bf[3] = lo[3];
        bf[4] = hi[0]; bf[5] = hi[1]; bf[6] = hi[2]; bf[7] = hi[3];
        // acc = bp*4096 + dot(x, -8192*w) = 4096 * (sqdist - |x|^2)
        acc = __builtin_amdgcn_mfma_scale_f32_32x32x64_f8f6f4(
            afr[ks], bf, acc, 0, 0, 0, 127, 0, 127);
      }
      __builtin_amdgcn_s_setprio(0);
      // pack (slot, lane) into the 10 noise bits of the mantissa; min_u32
      const uint32_t vslot = ((uint32_t)(kt * 2 + nb) << 5) | (uint32_t)l31;
#pragma unroll
      for (int j = 0; j < 16; ++j) {
        uint32_t p0 = __float_as_uint(acc[j]) | vslot;
        mp[j] = p0 < mp[j] ? p0 : mp[j];
      }
    }
    __builtin_amdgcn_sched_barrier(0);
    asm volatile("s_waitcnt vmcnt(0)" ::: "memory");
    __builtin_amdgcn_s_barrier();
    __builtin_amdgcn_sched_barrier(0);
  }

  // ---- cross-lane argmin over the 32 code-columns, write candidates ----
#pragma unroll
  for (int j = 0; j < 16; ++j) {
    uint32_t pv = mp[j];
#pragma unroll
    for (int o = 1; o < 32; o <<= 1) {
      uint32_t ov = (uint32_t)__shfl_xor((int)pv, o, 64);
      pv = ov < pv ? ov : pv;
    }
    if (l31 == 0) {
      uint32_t slot = (pv >> 5) & 31u, lw = pv & 31u;
      uint32_t kg = (uint32_t)k0 + (slot >> 1) * 64 + (slot & 1) * 32 + lw;
      int row = rb + wv * 32 + (j & 3) + 8 * (j >> 2) + 4 * h;
      cand[(size_t)row * KSPLIT + sp] = ((uint64_t)pv << 13) | (uint64_t)kg;
    }
  }
}

// ---------------- Kernel C: combine splits, gather, out, loss partials -------
__global__ void kout(const float* __restrict__ x, const float* __restrict__ wgt,
                     const uint64_t* __restrict__ cand, float* __restrict__ out,
                     float* __restrict__ partial) {
  const int t = threadIdx.x;
  const int rb = blockIdx.x * 64;
  __shared__ int sk[64];
  __shared__ float red[4];
  if (t < 64) {
    const uint64_t* c = cand + (size_t)(rb + t) * KSPLIT;
    uint64_t P = c[0];
#pragma unroll
    for (int i = 1; i < KSPLIT; ++i) P = c[i] < P ? c[i] : P;
    sk[t] = (int)(P & 8191u);
  }
  __syncthreads();
  float acc = 0.f;
  for (int r = 0; r < 64; ++r) {
    int k = sk[r];
    float qv = wgt[(size_t)k * DIM + t];
    float xv = x[(size_t)(rb + r) * DIM + t];
    out[(size_t)(rb + r) * DIM + t] = qv;
    float d = xv - qv;
    acc = fmaf(d, d, acc);
  }
  for (int o = 32; o; o >>= 1) acc += __shfl_down(acc, o, 64);
  if ((t & 63) == 0) red[t >> 6] = acc;
  __syncthreads();
  if (t == 0) partial[blockIdx.x] = red[0] + red[1] + red[2] + red[3];
}

// ---------------- Kernel D: final loss ---------------------------------------
__global__ void kloss(const float* __restrict__ partial, float* __restrict__ lossout) {
  const int t = threadIdx.x;
  float s = partial[t] + partial[t + 256];
  for (int o = 32; o; o >>= 1) s += __shfl_down(s, o, 64);
  __shared__ float red[4];
  if ((t & 63) == 0) red[t >> 6] = s;
  __syncthreads();
  if (t == 0) lossout[0] = 1.5f * (red[0] + red[1] + red[2] + red[3]) /
                           (float)((size_t)N_ROWS * DIM);
}

extern "C" void kernel_launch(void* const* d_in, const int* in_sizes, int n_in,
                              void* d_out, int out_size, void* d_ws, size_t ws_size,
                              hipStream_t stream) {
  const float* x   = (const float*)d_in[0];
  const float* wgt = (const float*)d_in[1];
  float* out = (float*)d_out;
  uint8_t* ws = (uint8_t*)d_ws;
  uint32_t* wb8     = (uint32_t*)ws;                                    // 2 MB
  float*    bp      = (float*)(ws + (2u << 20));                        // 32 KB
  uint64_t* cand    = (uint64_t*)(ws + (2u << 20) + (64u << 10));       // 2 MB
  float*    partial = (float*)(ws + (2u << 20) + (64u << 10) + (2u << 20)); // 2 KB

  kconv<<<KCODES / 4, 256, 0, stream>>>(wgt, wb8, bp);
  dim3 g(N_ROWS / BM, KSPLIT);
  kmain<<<g, THREADS, 0, stream>>>(x, wb8, bp, cand);
  kout<<<N_ROWS / 64, 256, 0, stream>>>(x, wgt, cand, out, partial);
  kloss<<<1, 256, 0, stream>>>(partial, out + (size_t)N_ROWS * DIM);
}